// Round 1
// baseline (98.473 us; speedup 1.0000x reference)
//
#include <hip/hip_runtime.h>

// x (N,D,L) f32, weight (K,D) f32, scale (1,) f32
// out (N,K,L) f32 = (||x||^2 + ||c||^2 - 2 x.c) / scale^2
#define N_ 32
#define D_ 128
#define L_ 3136
#define K_ 64

typedef _Float16 f16x8 __attribute__((ext_vector_type(8)));
typedef float    f32x4 __attribute__((ext_vector_type(4)));

// ---------------- prep: W -> fragment-ordered fp16 plane + ||c||^2 ----------------
// Fragment entry e = (dc*4+kt)*64 + lane holds 8 fp16:
//   W[kt*16 + (lane&15)][dc*32 + (lane>>4)*8 + j], j = 0..7
__global__ __launch_bounds__(64) void prep_kernel(
    const float* __restrict__ w,
    unsigned short* __restrict__ wh,
    float* __restrict__ csq)
{
    const int b = blockIdx.x, lane = threadIdx.x;
    if (b < 16) {
        const int dc = b >> 2, kt = b & 3;
        const int row = kt * 16 + (lane & 15);
        const int d0  = dc * 32 + (lane >> 4) * 8;
        const float* src = w + row * D_ + d0;
        __attribute__((aligned(16))) unsigned short h[8];
#pragma unroll
        for (int j = 0; j < 8; ++j) {
            _Float16 v = (_Float16)src[j];              // RNE f32->f16
            h[j] = *(const unsigned short*)&v;
        }
        const size_t off = (size_t)(b * 64 + lane) * 8;
        *(ushort4*)(wh + off)     = *(const ushort4*)(h);
        *(ushort4*)(wh + off + 4) = *(const ushort4*)(h + 4);
    } else {           // block 16: ||c_k||^2 (fp32, exact)
        const float* wr = w + lane * D_;
        float s = 0.f;
#pragma unroll
        for (int d = 0; d < D_; d += 4) {
            float4 v = *(const float4*)(wr + d);
            s = fmaf(v.x, v.x, s); s = fmaf(v.y, v.y, s);
            s = fmaf(v.z, v.z, s); s = fmaf(v.w, v.w, s);
        }
        csq[lane] = s;
    }
}

// ---------------- main: 64 l x 64 k x one n per block ----------------
// x tile (128d x 64l f32, 32 KB) staged via global_load_lds dwordx4 (16 B/lane,
// 1 KB/instr/wave, no VGPR round-trip). 16B-slot XOR swizzle (slot ^= quad(d))
// applied on the GLOBAL source address (LDS dest must stay lane-linear, m104/m173)
// makes the consume-phase ds_read_b32 exactly 2-way (= free).
// Split-half pipeline: counted s_waitcnt vmcnt(4) keeps the second x-half in
// flight while the first half is consumed; only 2 barriers in the kernel.
__global__ __launch_bounds__(256, 3) void enc_mfma_kernel(
    const float* __restrict__ x,
    const unsigned short* __restrict__ wh,
    const float* __restrict__ csqg,
    const float* __restrict__ scale,
    float* __restrict__ out)
{
    __shared__ __attribute__((aligned(16))) float lds_x[8192];           // 32 KB x tile
    __shared__ __attribute__((aligned(16))) unsigned short lds_w[8192];  // 16 KB W frags
    __shared__ float lds_csq[K_];

    const int t    = threadIdx.x;
    const int wave = t >> 6;
    const int lane = t & 63;
    const int col  = lane & 15;
    const int quad = lane >> 4;
    const int n    = blockIdx.y;
    const int l0   = blockIdx.x * 64;

    // ---- issue W frag stage (16 KB) + csq: flat lane-ordered copy ----
#pragma unroll
    for (int i = 0; i < 4; ++i) {
        const int c = wave * 4 + i;                        // chunk 0..15, wave-uniform
        __builtin_amdgcn_global_load_lds(
            (const __attribute__((address_space(1))) unsigned int*)(wh + (size_t)c * 512 + lane * 8),
            (__attribute__((address_space(3))) unsigned int*)&lds_w[c * 512],
            16, 0, 0);
    }
    if (wave == 0) {
        __builtin_amdgcn_global_load_lds(
            (const __attribute__((address_space(1))) unsigned int*)(csqg + lane),
            (__attribute__((address_space(3))) unsigned int*)lds_csq,
            4, 0, 0);
    }

    // ---- issue x tile stage: 2048 16B-chunks, chunk cid = i*256 + t ----
    // chunk (d = cid>>4, slot = cid&15) holds global l-group lg = slot ^ (quad(d)<<2)
    const float* xn = x + (size_t)n * D_ * L_ + l0;
#pragma unroll
    for (int i = 0; i < 8; ++i) {
        const int cid = i * 256 + t;
        const int d   = cid >> 4;                          // 0..127
        const int lg  = (cid & 15) ^ (((d >> 3) & 3) << 2); // XOR-swizzled source group
        __builtin_amdgcn_global_load_lds(
            (const __attribute__((address_space(1))) unsigned int*)(xn + (size_t)d * L_ + lg * 4),
            (__attribute__((address_space(3))) unsigned int*)&lds_x[i * 1024 + wave * 256],
            16, 0, 0);
    }

    f32x4 acc[4];
#pragma unroll
    for (int kt = 0; kt < 4; ++kt) acc[kt] = (f32x4){0.f, 0.f, 0.f, 0.f};
    float xsq = 0.f;

    // consume-phase LDS address: fidx(d) = d*64 + lbase, constant lbase per lane
    // (lane's d-set always has quad(d) == quad, so the XOR term is lane-constant).
    // bank = col + 16*((wave^quad)&1)  -> exactly 2 lanes/bank = conflict-free.
    const int wl    = wave * 16 + col;
    const int lbase = (((wl >> 2) ^ (quad << 2)) << 2) | (col & 3);

    // ---- wait: W + csq + x half 1 (d 0..63) resident; x half 2 still in flight ----
    asm volatile("s_waitcnt vmcnt(4)" ::: "memory");
    __builtin_amdgcn_s_barrier();
    __builtin_amdgcn_sched_barrier(0);

#pragma unroll
    for (int dc = 0; dc < 2; ++dc) {
        const float* xp = &lds_x[(dc * 32 + quad * 8) * 64 + lbase];
        float xv[8];
#pragma unroll
        for (int j = 0; j < 8; ++j) xv[j] = xp[j * 64];
        union { f16x8 v; _Float16 e[8]; } af;
#pragma unroll
        for (int j = 0; j < 8; ++j) {
            xsq = fmaf(xv[j], xv[j], xsq);     // exact fp32 ||x||^2
            af.e[j] = (_Float16)xv[j];         // RNE f32->f16
        }
#pragma unroll
        for (int kt = 0; kt < 4; ++kt) {
            f16x8 bf = *(const f16x8*)&lds_w[((dc * 4 + kt) * 64 + lane) * 8];
            acc[kt] = __builtin_amdgcn_mfma_f32_16x16x32_f16(af.v, bf, acc[kt], 0, 0, 0);
        }
    }

    // ---- wait: x half 2 (d 64..127) resident ----
    asm volatile("s_waitcnt vmcnt(0)" ::: "memory");
    __builtin_amdgcn_s_barrier();
    __builtin_amdgcn_sched_barrier(0);

#pragma unroll
    for (int dc = 2; dc < 4; ++dc) {
        const float* xp = &lds_x[(dc * 32 + quad * 8) * 64 + lbase];
        float xv[8];
#pragma unroll
        for (int j = 0; j < 8; ++j) xv[j] = xp[j * 64];
        union { f16x8 v; _Float16 e[8]; } af;
#pragma unroll
        for (int j = 0; j < 8; ++j) {
            xsq = fmaf(xv[j], xv[j], xsq);
            af.e[j] = (_Float16)xv[j];
        }
#pragma unroll
        for (int kt = 0; kt < 4; ++kt) {
            f16x8 bf = *(const f16x8*)&lds_w[((dc * 4 + kt) * 64 + lane) * 8];
            acc[kt] = __builtin_amdgcn_mfma_f32_16x16x32_f16(af.v, bf, acc[kt], 0, 0, 0);
        }
    }

    // ---- ||x||^2 full reduce over quads; fetch the 4 rows this lane stores ----
    xsq += __shfl_xor(xsq, 16, 64);
    xsq += __shfl_xor(xsq, 32, 64);            // every lane: xsq for its own col
    float xs[4];
#pragma unroll
    for (int r = 0; r < 4; ++r)
        xs[r] = __shfl(xsq, quad * 4 + r, 64); // value for l-row = quad*4+r

    // ---- epilogue: fuse terms, direct float4 stores from acc ----
    // D layout: col(lane&15)=k, row(quad*4+r)=l => acc[kt] holds 4 consecutive l's
    const float sc = scale[0];
    const float inv_s2 = 1.0f / (sc * sc);
    float* op = out + (size_t)n * K_ * L_ + l0 + wave * 16 + quad * 4;
#pragma unroll
    for (int kt = 0; kt < 4; ++kt) {
        const float cs = lds_csq[kt * 16 + col];   // same-address across quads: broadcast
        float4 v;
        v.x = (xs[0] + cs - 2.0f * acc[kt][0]) * inv_s2;
        v.y = (xs[1] + cs - 2.0f * acc[kt][1]) * inv_s2;
        v.z = (xs[2] + cs - 2.0f * acc[kt][2]) * inv_s2;
        v.w = (xs[3] + cs - 2.0f * acc[kt][3]) * inv_s2;
        *(float4*)(op + (size_t)(kt * 16 + col) * L_) = v;
    }
}

extern "C" void kernel_launch(void* const* d_in, const int* in_sizes, int n_in,
                              void* d_out, int out_size, void* d_ws, size_t ws_size,
                              hipStream_t stream) {
    const float* x     = (const float*)d_in[0];
    const float* w     = (const float*)d_in[1];
    const float* scale = (const float*)d_in[2];
    float* out = (float*)d_out;

    // d_ws carve: [0,16K) W fp16 frags, [16K,+256) csq
    unsigned short* wh  = (unsigned short*)d_ws;
    float*          csq = (float*)((char*)d_ws + 16384);

    prep_kernel<<<17, 64, 0, stream>>>(w, wh, csq);
    dim3 grid(L_ / 64, N_);   // (49, 32) = 1568 blocks, no tail
    enc_mfma_kernel<<<grid, 256, 0, stream>>>(x, wh, csq, scale, out);
}